// Round 2
// baseline (548.609 us; speedup 1.0000x reference)
//
#include <hip/hip_runtime.h>
#include <hip/hip_bf16.h>

// ---- problem constants ----
#define IN_CH    31
#define OUT_CH   31
#define COEF_LEN 7688           // 31*31*8
#define NPIX     16384          // 128*128
#define KPAD     288            // 279 conv weights + 1 bias col + 8 zero pad
#define NFRAG    20             // 320 param cols / 16
#define KSTEPS   9              // 288/32
#define CHUNKS   31             // one per input channel
#define PLDS_STRIDE 296         // 288 + 8 pad bf16 (592B row: 16B aligned, bank-staggered)
#define XS_STRIDE   68
#define LDS_BYTES (64*PLDS_STRIDE*2 + 31*3*XS_STRIDE*4)   // 37888 + 25296 = 63184

using f32x4 = __attribute__((ext_vector_type(4))) float;
using s16x8 = __attribute__((ext_vector_type(8))) short;

__device__ __forceinline__ unsigned short f2bf(float f) {
    unsigned int u = __float_as_uint(f);
    unsigned int r = (u + 0x7FFFu + ((u >> 16) & 1u)) >> 16;
    return (unsigned short)r;
}

// ---------------------------------------------------------------------------
// Pack gen_w/gen_b into bf16 fragment layout (used as MFMA *A* operand):
//   Bpack[i][nf][ks][lane][8]   (16B per lane -> one coalesced dwordx4 load)
// param row c = nf*16 + (lane&15); o = c/10, j = c%10
//   j in 0..7 -> coef[i][o][j]; j==8 -> univ[i][o]; j==9 -> res[i][o]
// k = ks*32 + (lane>>4)*8 + jj; k<279 -> gen_w[p][k]; k==279 -> gen_b[p]; else 0
// ---------------------------------------------------------------------------
__global__ void pack_kernel(const float* __restrict__ gw, const float* __restrict__ gb,
                            unsigned short* __restrict__ bp) {
    int tt = blockIdx.x * 256 + threadIdx.x;
    if (tt >= CHUNKS * NFRAG * KSTEPS * 64) return;
    int lane = tt & 63;
    int t2 = tt >> 6;
    int ks = t2 % KSTEPS;
    int t3 = t2 / KSTEPS;
    int nf = t3 % NFRAG;
    int i  = t3 / NFRAG;

    int c = nf * 16 + (lane & 15);
    int o = c / 10, j = c - o * 10;
    int kbase = ks * 32 + (lane >> 4) * 8;

    int p = -1;
    if (o < OUT_CH) {
        if (j < 8)       p = i * 248 + o * 8 + j;
        else if (j == 8) p = COEF_LEN + i * 31 + o;
        else             p = COEF_LEN + 961 + i * 31 + o;
    }
    s16x8 v;
    #pragma unroll
    for (int jj = 0; jj < 8; ++jj) {
        int k = kbase + jj;
        float val = 0.f;
        if (p >= 0) {
            if (k < 279)       val = gw[p * 279 + k];
            else if (k == 279) val = gb[p];
        }
        v[jj] = (short)f2bf(val);
    }
    *reinterpret_cast<s16x8*>(bp + (size_t)tt * 8) = v;
}

// ---------------------------------------------------------------------------
// Fused conv-GEMM + KAN epilogue, swapped operands (params=A, patch=B).
// Block = 64 pixels, 512 threads = 8 waves: wm (2, param halves of 10 frags)
// x wn (4, pixel groups of 16). Lane owns ONE pixel (wn*16 + lane&15) and
// param-row quartile q = lane>>4. Epilogue is register+shuffle only; the
// 31-chunk loop has NO barriers.
// ---------------------------------------------------------------------------
__global__ void __launch_bounds__(512, 2)
main_kernel(const float* __restrict__ x, const unsigned short* __restrict__ bp,
            float* __restrict__ out) {
    extern __shared__ char smem[];
    unsigned short* plds = (unsigned short*)smem;               // [64][296] bf16
    float* xs = (float*)(smem + 64 * PLDS_STRIDE * 2);          // [31][3][68] staging

    const int tid = threadIdx.x;
    const int pix_base = blockIdx.x * 64;
    const int h0 = pix_base >> 7;
    const int w0 = pix_base & 127;

    // phase 0: stage x slab (rows h0-1..h0+1, cols w0-1..w0+64, zero-padded)
    for (int idx = tid; idx < 31 * 3 * 66; idx += 512) {
        int ci = idx / 198;
        int rem = idx - ci * 198;
        int ry = rem / 66;
        int cx = rem - ry * 66;
        int hh = h0 - 1 + ry;
        int ww = w0 - 1 + cx;
        float v = 0.f;
        if ((unsigned)hh < 128u && (unsigned)ww < 128u)
            v = x[ci * NPIX + hh * 128 + ww];
        xs[(ci * 3 + ry) * XS_STRIDE + cx] = v;
    }
    __syncthreads();

    // phase 1: build bf16 patch tile plds[n][k], k=(ci*9+ky*3+kx), col 279 = 1.0 (bias)
    for (int idx = tid; idx < 64 * KPAD; idx += 512) {
        int n = idx / KPAD;
        int k = idx - n * KPAD;
        unsigned short val = 0;
        if (k < 279) {
            int ci = k / 9;
            int r = k - ci * 9;
            int ky = r / 3;
            int kx = r - ky * 3;
            val = f2bf(xs[(ci * 3 + ky) * XS_STRIDE + n + kx]);
        } else if (k == 279) {
            val = 0x3F80;  // 1.0f in bf16
        }
        plds[n * PLDS_STRIDE + k] = val;
    }
    __syncthreads();
    // ---- no more barriers for the rest of the kernel ----

    const int lane = tid & 63;
    const int wave = tid >> 6;
    const int wm = wave >> 2;       // 0..1: param frags [wm*10, wm*10+10)
    const int wn = wave & 3;        // 0..3: pixels [wn*16, wn*16+16)
    const int q = lane >> 4;        // param-row quartile within each 16-frag

    const int p_local = wn * 16 + (lane & 15);
    const int p_glob = pix_base + p_local;
    const int prow_base = p_local * PLDS_STRIDE + q * 8;
    const int lane8 = lane * 8;

    const unsigned short* bwm = bp + (size_t)(wm * 10) * (KSTEPS * 512);

    float oacc[4] = {0.f, 0.f, 0.f, 0.f};

    #pragma unroll 1
    for (int i = 0; i < CHUNKS; ++i) {
        // x value for this lane's pixel, channel i (hides under the MFMA block)
        float xv = x[i * NPIX + p_glob];

        f32x4 acc[10];
        #pragma unroll
        for (int f = 0; f < 10; ++f) acc[f] = (f32x4){0.f, 0.f, 0.f, 0.f};

        const unsigned short* bchunk = bwm + (size_t)i * (NFRAG * KSTEPS * 512);
        #pragma unroll
        for (int ks = 0; ks < KSTEPS; ++ks) {
            s16x8 pf = *reinterpret_cast<const s16x8*>(plds + prow_base + ks * 32);
            #pragma unroll
            for (int f = 0; f < 10; ++f) {
                s16x8 av = *reinterpret_cast<const s16x8*>(
                    bchunk + f * (KSTEPS * 512) + ks * 512 + lane8);
                acc[f] = __builtin_amdgcn_mfma_f32_16x16x32_bf16(av, pf, acc[f], 0, 0, 0);
            }
        }

        // ---- register epilogue: closed-form cubic B-spline + silu residual ----
        float u = (xv + 1.0f) * 2.5f;
        float cf = floorf(u);
        cf = fminf(fmaxf(cf, 0.f), 4.f);
        int cc = (int)cf;
        float t = u - cf;
        float omt = 1.f - t;
        float t2v = t * t, t3v = t2v * t;
        float bw0 = omt * omt * omt * (1.f / 6.f);
        float bw1 = (3.f * t3v - 6.f * t2v + 4.f) * (1.f / 6.f);
        float bw2 = (-3.f * t3v + 3.f * t2v + 3.f * t + 1.f) * (1.f / 6.f);
        float bw3 = t3v * (1.f / 6.f);
        float sl = xv / (1.f + __expf(-xv));

        float w[8];
        #pragma unroll
        for (int j = 0; j < 8; ++j) {
            float wv = 0.f;
            wv = (j == cc)     ? bw0 : wv;
            wv = (j == cc + 1) ? bw1 : wv;
            wv = (j == cc + 2) ? bw2 : wv;
            wv = (j == cc + 3) ? bw3 : wv;
            w[j] = wv;
        }

        #pragma unroll
        for (int ol = 0; ol < 16; ++ol) {
            float sp = 0.f;
            #pragma unroll
            for (int j = 0; j < 8; ++j) {
                const int cl = 10 * ol + j;           // local param row
                const int f = cl >> 4;
                const int idx = cl & 15;
                const int qj = idx >> 2;
                const int r = idx & 3;
                float v = (q == qj) ? acc[f][r] : 0.f;
                sp = fmaf(v, w[j], sp);
            }
            // sum partials across the 4-lane group (same pixel, quartiles 0..3)
            sp += __shfl_xor(sp, 16);
            sp += __shfl_xor(sp, 32);
            const int cu = 10 * ol + 8;               // univ row (res = cu+1, same lane)
            const int fu = cu >> 4;
            const int idxu = cu & 15;
            const int qu = idxu >> 2;
            const int ru = idxu & 3;
            if (q == qu) {
                const int slot = ol >> 2;             // static: 4 o's per quartile
                oacc[slot] = fmaf(acc[fu][ru], sp,
                             fmaf(sl, acc[fu][ru + 1], oacc[slot]));
            }
        }
    }

    // write out: (1, 31, 128, 128); o = wm*16 + ol, stored by its owning quartile
    #pragma unroll
    for (int ol = 0; ol < 16; ++ol) {
        const int o = wm * 16 + ol;
        const int qu = ((10 * ol + 8) & 15) >> 2;
        if (o < OUT_CH && q == qu)
            out[o * NPIX + p_glob] = oacc[ol >> 2];
    }
}

extern "C" void kernel_launch(void* const* d_in, const int* in_sizes, int n_in,
                              void* d_out, int out_size, void* d_ws, size_t ws_size,
                              hipStream_t stream) {
    const float* x  = (const float*)d_in[0];   // (1,31,128,128)
    const float* gw = (const float*)d_in[1];   // (9610,31,3,3)
    const float* gb = (const float*)d_in[2];   // (9610,)
    float* outp = (float*)d_out;               // (1,31,128,128)
    unsigned short* bpack = (unsigned short*)d_ws;  // 5,713,920 bytes

    hipFuncSetAttribute((const void*)main_kernel,
                        hipFuncAttributeMaxDynamicSharedMemorySize, LDS_BYTES);

    pack_kernel<<<1395, 256, 0, stream>>>(gw, gb, bpack);
    main_kernel<<<256, 512, LDS_BYTES, stream>>>(x, bpack, outp);
}

// Round 3
// 197.248 us; speedup vs baseline: 2.7813x; 2.7813x over previous
//
#include <hip/hip_runtime.h>
#include <hip/hip_bf16.h>

// ---- problem constants ----
#define OUT_CH   31
#define COEF_LEN 7688           // 31*31*8
#define NPIX     16384          // 128*128
#define CHUNKS   31             // one per input channel
#define NFRG     24             // param fragments per chunk (384 padded rows)
#define NR       9              // K-steps: r = ky*3+kx; K = 9*32 (k = r*32 + ci)
#define FRAG_B   1024           // bytes per fragment per r (64 lanes x 16B)
#define CHUNK_B  (NFRG*NR*FRAG_B)      // 221184
#define BP2_B    ((size_t)CHUNKS*CHUNK_B) // 6,856,704
#define BIAS_ELE (CHUNKS*NFRG*16)      // 11904 f32

// LDS layout
#define PBUF_B      24576              // NFRG * FRAG_B (one r-step, all frags)
#define SLAB_OFF    (2*PBUF_B)         // 49152
#define SLAB_STRIDE 40                 // u16 slots per (row,col): 80B, 16B-aligned, 20-bank stagger
#define SLAB_B      (4*130*SLAB_STRIDE*2)  // 41600
#define OACC_OFF    (SLAB_OFF + SLAB_B)    // 90752
#define OACC_STRIDE 33
#define OACC_B      (256*OACC_STRIDE*4)    // 33792
#define LDS_BYTES   (OACC_OFF + OACC_B)    // 124544

using f32x4 = __attribute__((ext_vector_type(4))) float;
using s16x8 = __attribute__((ext_vector_type(8))) short;

__device__ __forceinline__ unsigned short f2bf(float f) {
    unsigned int u = __float_as_uint(f);
    unsigned int r = (u + 0x7FFFu + ((u >> 16) & 1u)) >> 16;
    return (unsigned short)r;
}

// ---------------------------------------------------------------------------
// Pack gen_w/gen_b into bf16 A-fragment layout + bias table.
//  bp2[i][f][r][lane][8] bf16: MFMA A-frag for chunk i, frag f, K-step r.
//   M-row m = lane&15; k-in-step = (lane>>4)*8 + jj = input channel ci.
//   param identity: o = (m>>2)*8 + f/3, jslot = (f%3)*4 + (m&3)
//     jslot 0..7 = coef j, 8 = univ, 9 = res, 10..11 = zero pad
//   value = gw[p][ci][r] (r = ky*3+kx), zero for ci==31 / o==31 / pad slots.
//  bias_pk[i][f][m] f32 = gb[p] (acc init -> bias added exactly once).
// ---------------------------------------------------------------------------
__global__ void pack_kernel(const float* __restrict__ gw, const float* __restrict__ gb,
                            unsigned short* __restrict__ bp, float* __restrict__ bias_pk) {
    const long NU = (long)CHUNKS * NFRG * NR * 64;
    long tt = (long)blockIdx.x * 256 + threadIdx.x;
    if (tt < NU) {
        int lane = (int)(tt & 63);
        long t2 = tt >> 6;
        int r = (int)(t2 % NR); t2 /= NR;
        int f = (int)(t2 % NFRG);
        int i = (int)(t2 / NFRG);
        int m = lane & 15, q8 = lane >> 4;
        int o = (m >> 2) * 8 + f / 3;
        int jslot = (f % 3) * 4 + (m & 3);
        s16x8 v;
        #pragma unroll
        for (int jj = 0; jj < 8; ++jj) {
            int ci = q8 * 8 + jj;
            float val = 0.f;
            if (ci < 31 && o < OUT_CH && jslot < 10) {
                int p;
                if (jslot < 8)       p = i * 248 + o * 8 + jslot;
                else if (jslot == 8) p = COEF_LEN + i * 31 + o;
                else                 p = COEF_LEN + 961 + i * 31 + o;
                val = gw[(long)p * 279 + ci * 9 + r];
            }
            v[jj] = (short)f2bf(val);
        }
        *reinterpret_cast<s16x8*>(bp + tt * 8) = v;
    } else if (tt < NU + BIAS_ELE) {
        long u = tt - NU;
        int m = (int)(u & 15);
        long t2 = u >> 4;
        int f = (int)(t2 % NFRG);
        int i = (int)(t2 / NFRG);
        int o = (m >> 2) * 8 + f / 3;
        int jslot = (f % 3) * 4 + (m & 3);
        float val = 0.f;
        if (o < OUT_CH && jslot < 10) {
            int p;
            if (jslot < 8)       p = i * 248 + o * 8 + jslot;
            else if (jslot == 8) p = COEF_LEN + i * 31 + o;
            else                 p = COEF_LEN + 961 + i * 31 + o;
            val = gb[p];
        }
        bias_pk[u] = val;
    }
}

__device__ __forceinline__ void stage_step(const unsigned short* __restrict__ bp2,
                                           char* smem, int bufsel, int ic, int r, int tid) {
    #pragma unroll
    for (int s = 0; s < 3; ++s) {
        int u = tid + 512 * s;                 // 1536 units of 16B = 24KB
        int f = u >> 6;
        int l = u & 63;
        const char* gsrc = (const char*)bp2 +
            ((((size_t)ic * NFRG + f) * NR + r) * 64 + l) * 16;
        char* ldst = smem + bufsel * PBUF_B + u * 16;   // wave-uniform base + lane*16
        __builtin_amdgcn_global_load_lds(
            (const __attribute__((address_space(1))) void*)gsrc,
            (__attribute__((address_space(3))) void*)ldst, 16, 0, 0);
    }
}

// ---------------------------------------------------------------------------
// Fused conv-GEMM + KAN epilogue.
// Grid 256 = 64 pixel-blocks (256 px = 2 image rows) x 4 chunk-groups.
//   cg = bid&3 -> all blocks on one XCD share the same 1.73MB param slice (L2-resident).
// 8 waves = 2 wm (12 frags each) x 4 wn (64 px = 4 pg of 16).
// Per (chunk, r) step: params staged to LDS (global_load_lds, double-buffered),
// patch B-frags read directly from compact slab (16B contiguous per lane).
// Epilogue fully lane-local (o = q*8 + wm*4 + t4); partials in padded LDS;
// final atomicAdd into memset-zeroed out.
// ---------------------------------------------------------------------------
__global__ void __launch_bounds__(512, 2)
main_kernel(const float* __restrict__ x, const unsigned short* __restrict__ bp2,
            const float* __restrict__ bias_pk, float* __restrict__ out) {
    extern __shared__ char smem[];
    const int tid = threadIdx.x;
    const int bid = blockIdx.x;
    const int cg = bid & 3;
    const int pb = bid >> 2;
    const int c0 = cg * 8;
    const int c1 = (c0 + 8 < CHUNKS) ? c0 + 8 : CHUNKS;
    const int H0 = pb * 2;

    // build slab: [rr 0..3][cc 0..129][slot 0..39] bf16; rr=image row H0-1+rr, cc=image col cc-1
    unsigned short* slab = (unsigned short*)(smem + SLAB_OFF);
    for (int idx = tid; idx < 4 * 130 * 32; idx += 512) {
        int slot = idx & 31;
        int t = idx >> 5;
        int cc = t % 130;
        int rr = t / 130;
        int hh = H0 - 1 + rr, ww = cc - 1;
        float v = 0.f;
        if (slot < 31 && (unsigned)hh < 128u && (unsigned)ww < 128u)
            v = x[slot * NPIX + hh * 128 + ww];
        slab[(rr * 130 + cc) * SLAB_STRIDE + slot] = f2bf(v);
    }
    // zero output partial accumulator
    float* oaccl = (float*)(smem + OACC_OFF);
    for (int idx = tid; idx < 256 * OACC_STRIDE; idx += 512) oaccl[idx] = 0.f;

    // prologue: stage first step
    stage_step(bp2, smem, 0, c0, 0, tid);
    __syncthreads();

    const int lane = tid & 63;
    const int wave = tid >> 6;
    const int wm = wave >> 2;       // 0..1: frags [wm*12, wm*12+12)
    const int wn = wave & 3;        // 0..3: pixels [wn*64, wn*64+64)
    const int q = lane >> 4;
    const int pix16 = lane & 15;
    const int hloc = wn >> 1;                    // wave-uniform pixel row within block
    const int wbase = (wn & 1) * 64 + pix16;

    int sa[4], pxl[4];
    #pragma unroll
    for (int pg = 0; pg < 4; ++pg) {
        pxl[pg] = wn * 64 + pg * 16 + pix16;
        sa[pg] = SLAB_OFF + (hloc * 130 + wbase + pg * 16) * (SLAB_STRIDE * 2) + q * 16;
    }

    int cur = 0;
    #pragma unroll 1
    for (int ic = c0; ic < c1; ++ic) {
        // acc init = bias (added exactly once per param, per owning chunk-group)
        f32x4 acc[12][4];
        const float* bb = bias_pk + ((size_t)ic * NFRG + wm * 12) * 16 + q * 4;
        #pragma unroll
        for (int fl = 0; fl < 12; ++fl) {
            f32x4 b = *reinterpret_cast<const f32x4*>(bb + fl * 16);
            #pragma unroll
            for (int pg = 0; pg < 4; ++pg) acc[fl][pg] = b;
        }
        float xvr[4];
        #pragma unroll
        for (int pg = 0; pg < 4; ++pg)
            xvr[pg] = x[(size_t)ic * NPIX + pb * 256 + pxl[pg]];

        #pragma unroll
        for (int r = 0; r < 9; ++r) {
            // stage next step into the other buffer (loads fly across this step's MFMAs)
            int nic = (r < 8) ? ic : ic + 1;
            int nr  = (r < 8) ? r + 1 : 0;
            if (nic < c1) stage_step(bp2, smem, cur ^ 1, nic, nr, tid);

            const int roff = ((r / 3) * 130 + (r % 3)) * (SLAB_STRIDE * 2);
            s16x8 pbv[4];
            #pragma unroll
            for (int pg = 0; pg < 4; ++pg)
                pbv[pg] = *reinterpret_cast<const s16x8*>(smem + sa[pg] + roff);

            #pragma unroll
            for (int fl = 0; fl < 12; ++fl) {
                s16x8 pa = *reinterpret_cast<const s16x8*>(
                    smem + cur * PBUF_B + (wm * 12 + fl) * FRAG_B + lane * 16);
                #pragma unroll
                for (int pg = 0; pg < 4; ++pg)
                    acc[fl][pg] = __builtin_amdgcn_mfma_f32_16x16x32_bf16(pa, pbv[pg], acc[fl][pg], 0, 0, 0);
            }

            if (r == 8) {
                // lane-local epilogue: closed-form cubic B-spline + silu residual
                #pragma unroll
                for (int pg = 0; pg < 4; ++pg) {
                    float xv = xvr[pg];
                    float u5 = (xv + 1.0f) * 2.5f;
                    float cf = fminf(fmaxf(floorf(u5), 0.f), 4.f);
                    int ccb = (int)cf;
                    float t = u5 - cf;
                    float omt = 1.f - t;
                    float t2v = t * t, t3v = t2v * t;
                    float bw0 = omt * omt * omt * (1.f / 6.f);
                    float bw1 = (3.f * t3v - 6.f * t2v + 4.f) * (1.f / 6.f);
                    float bw2 = (-3.f * t3v + 3.f * t2v + 3.f * t + 1.f) * (1.f / 6.f);
                    float bw3 = t3v * (1.f / 6.f);
                    float sl = xv / (1.f + __expf(-xv));
                    float w[8];
                    #pragma unroll
                    for (int j = 0; j < 8; ++j) {
                        float wv = 0.f;
                        wv = (j == ccb)     ? bw0 : wv;
                        wv = (j == ccb + 1) ? bw1 : wv;
                        wv = (j == ccb + 2) ? bw2 : wv;
                        wv = (j == ccb + 3) ? bw3 : wv;
                        w[j] = wv;
                    }
                    float* orow = oaccl + pxl[pg] * OACC_STRIDE;
                    #pragma unroll
                    for (int t4 = 0; t4 < 4; ++t4) {
                        float sp = 0.f;
                        #pragma unroll
                        for (int j = 0; j < 8; ++j)
                            sp = fmaf(w[j], acc[3 * t4 + (j >> 2)][pg][j & 3], sp);
                        float uv = acc[3 * t4 + 2][pg][0];
                        float rv = acc[3 * t4 + 2][pg][1];
                        int o = q * 8 + wm * 4 + t4;
                        orow[o] += uv * sp + sl * rv;   // lane-private word, no race
                    }
                }
            }
            __syncthreads();
            cur ^= 1;
        }
    }

    // final: atomic-accumulate this chunk-group's partials into out
    #pragma unroll
    for (int pg = 0; pg < 4; ++pg) {
        #pragma unroll
        for (int t4 = 0; t4 < 4; ++t4) {
            int o = q * 8 + wm * 4 + t4;
            if (o < OUT_CH)
                atomicAdd(out + (size_t)o * NPIX + pb * 256 + pxl[pg],
                          oaccl[pxl[pg] * OACC_STRIDE + o]);
        }
    }
}

extern "C" void kernel_launch(void* const* d_in, const int* in_sizes, int n_in,
                              void* d_out, int out_size, void* d_ws, size_t ws_size,
                              hipStream_t stream) {
    const float* x  = (const float*)d_in[0];   // (1,31,128,128)
    const float* gw = (const float*)d_in[1];   // (9610,31,3,3)
    const float* gb = (const float*)d_in[2];   // (9610,)
    float* outp = (float*)d_out;               // (1,31,128,128)
    unsigned short* bpack = (unsigned short*)d_ws;          // 6,856,704 B
    float* bias_pk = (float*)((char*)d_ws + BP2_B);         // + 47,616 B

    hipFuncSetAttribute((const void*)main_kernel,
                        hipFuncAttributeMaxDynamicSharedMemorySize, LDS_BYTES);

    hipMemsetAsync(d_out, 0, (size_t)out_size * sizeof(float), stream);

    const long NU = (long)CHUNKS * NFRG * NR * 64;
    int pack_blocks = (int)((NU + BIAS_ELE + 255) / 256);   // 1721
    pack_kernel<<<pack_blocks, 256, 0, stream>>>(gw, gb, bpack, bias_pk);
    main_kernel<<<256, 512, LDS_BYTES, stream>>>(x, bpack, bias_pk, outp);
}